// Round 11
// baseline (281.212 us; speedup 1.0000x reference)
//
#include <hip/hip_runtime.h>
#include <hip/hip_bf16.h>

#define F 256
#define V 512
#define NB 8   // texture batch
#define NC 8   // n_code
#define NH 4
#define DQ 64
#define EPS 1e-6f

typedef __hip_bfloat16 bf16;
typedef __attribute__((ext_vector_type(8))) short short8;   // 8 bf16 MFMA operand
typedef __attribute__((ext_vector_type(4))) float f32x4;    // MFMA accumulator
typedef __attribute__((ext_vector_type(4))) unsigned uint4v;

__device__ __forceinline__ float b2f(bf16 x){ return __bfloat162float(x); }
__device__ __forceinline__ float shf(short s){
    return __bfloat162float(__builtin_bit_cast(bf16, (unsigned short)s));
}

#define MFMA(a,b,c) __builtin_amdgcn_mfma_f32_16x16x32_bf16((a),(b),(c),0,0,0)

__device__ __forceinline__ unsigned pack2bf(float a, float b){
    unsigned short ua = __builtin_bit_cast(unsigned short, __float2bfloat16(a));
    unsigned short ub = __builtin_bit_cast(unsigned short, __float2bfloat16(b));
    return (unsigned)ua | ((unsigned)ub << 16);
}

// ---- K0: cast the six 256x256 fp32 weights -> bf16 ws. order Wq,Wk,Wv,Wo,W1,W2.
__global__ void castw_kernel(const float* __restrict__ w0, const float* __restrict__ w1,
                             const float* __restrict__ w2, const float* __restrict__ w3,
                             const float* __restrict__ w4, const float* __restrict__ w5,
                             bf16* __restrict__ dst){
    int which = blockIdx.x >> 8;
    int idx = ((blockIdx.x & 255) << 8) | threadIdx.x;
    const float* s = which==0?w0: which==1?w1: which==2?w2: which==3?w3: which==4?w4: w5;
    dst[which * (F*F) + idx] = __float2bfloat16(s[idx]);
}

// ---- K1: LayerNorm -> bf16 normalized rows; also bf16 copy of texture_map (tb).
// One-pass (sum, sumsq) wave-shuffle reduction; 1 barrier.
__global__ void ln_kernel(const float* __restrict__ code, const float* __restrict__ tex,
                          const float* __restrict__ ln1_g, const float* __restrict__ ln1_b,
                          const float* __restrict__ ln2_g, const float* __restrict__ ln2_b,
                          bf16* __restrict__ cn, bf16* __restrict__ tn, bf16* __restrict__ tb){
    __shared__ float redS[4], redQ[4];
    int r = blockIdx.x, t = threadIdx.x;
    int is_tex = r >> 12;
    int row = r & 4095;
    const float* src = is_tex ? tex : code;
    const float* g   = is_tex ? ln2_g : ln1_g;
    const float* be  = is_tex ? ln2_b : ln1_b;
    bf16* dst        = is_tex ? tn : cn;

    float x = src[row * F + t];
    if (is_tex) tb[row * F + t] = __float2bfloat16(x);
    float s = x, q = x * x;
    #pragma unroll
    for(int m = 1; m < 64; m <<= 1){ s += __shfl_xor(s, m); q += __shfl_xor(q, m); }
    if ((t & 63) == 0){ redS[t >> 6] = s; redQ[t >> 6] = q; }
    __syncthreads();
    float S = redS[0] + redS[1] + redS[2] + redS[3];
    float Q = redQ[0] + redQ[1] + redQ[2] + redQ[3];
    float mu = S * (1.0f / F);
    float var = Q * (1.0f / F) - mu * mu;
    float rs = rsqrtf(var + EPS);
    dst[row * F + t] = __float2bfloat16((x - mu) * rs * g[t] + be[t]);
}

// ---- K2: QKV MFMA GEMM, M=4096 N=256 K=256. grid (64, 4, 3), 4 waves of 16x64.
// z=0: Q -> qn row-major; z=1: K -> k4 A-frag layout; z=2: V -> v4 chunk-tiled.
__global__ __launch_bounds__(256) void qkvgemm_kernel(const bf16* __restrict__ cn,
                                                      const bf16* __restrict__ tn,
                                                      const bf16* __restrict__ wbf,
                                                      const float* __restrict__ bq,
                                                      const float* __restrict__ bk,
                                                      const float* __restrict__ bv,
                                                      bf16* __restrict__ qn,
                                                      bf16* __restrict__ k4,
                                                      bf16* __restrict__ v4){
    int which = blockIdx.z;
    const bf16* in   = (which == 0) ? tn : cn;
    const bf16* wb   = wbf + which * (F * F);
    const float* bias = (which == 0) ? bq : (which == 1) ? bk : bv;

    int w = threadIdx.x >> 6, lane = threadIdx.x & 63;
    int lg = lane >> 4, li = lane & 15;
    int rowbase = blockIdx.x * 64 + w * 16;
    int colbase = blockIdx.y * 64;

    f32x4 acc[4];
    #pragma unroll
    for(int ni = 0; ni < 4; ni++) acc[ni] = (f32x4){0.f,0.f,0.f,0.f};

    #pragma unroll
    for(int kc = 0; kc < 8; kc++){
        short8 a = *(const short8*)(in + (rowbase + li) * F + kc * 32 + lg * 8);
        #pragma unroll
        for(int ni = 0; ni < 4; ni++){
            short8 bb = *(const short8*)(wb + (colbase + ni * 16 + li) * F + kc * 32 + lg * 8);
            acc[ni] = MFMA(a, bb, acc[ni]);
        }
    }

    #pragma unroll
    for(int r = 0; r < 4; r++){
        int row = rowbase + lg * 4 + r;
        #pragma unroll
        for(int ni = 0; ni < 4; ni++){
            int col = colbase + ni * 16 + li;
            float val = acc[ni][r] + bias[col];
            if (which == 0)
                qn[row * F + col] = __float2bfloat16(val);
            else if (which == 1){
                int n = row >> 9, keyl = row & (V - 1);
                int kc2 = keyl >> 5, kt = (keyl >> 4) & 1, lip = keyl & 15;
                int hh = col >> 6, ks = (col >> 5) & 1, lgp = (col >> 3) & 3, j = col & 7;
                int fi = ((n * 16 + kc2) * 2 + kt) * 8 + hh * 2 + ks;
                k4[fi * 512 + lgp * 128 + lip * 8 + j] = __float2bfloat16(val);
            } else {
                int n = row >> 9, key = row & (V - 1);
                v4[(((n * 16 + (key >> 5)) * F) + col) * 32 + (key & 31)] = __float2bfloat16(val);
            }
        }
    }
}

// ---- K3 MEGA: flash attention + Wo + tex residual + ffln LN + W1/ReLU + W2 + residual -> out.
// grid (64, 32): x = (n | b<<3) [XCD swizzle], y = qtile (16 q-rows). 256 thr = 4 waves = 4 heads.
// LDS = 8.4 KB (xs only) -> ~7 blocks/CU co-resident. LN stats via 16-lane shuffles.
__global__ __launch_bounds__(256, 7) void attn_mlp_kernel(const bf16* __restrict__ qn,
                                                          const bf16* __restrict__ k4,
                                                          const bf16* __restrict__ v4,
                                                          const bf16* __restrict__ wbf,
                                                          const float* __restrict__ bo,
                                                          const bf16* __restrict__ tb,
                                                          const float* __restrict__ ffg,
                                                          const float* __restrict__ ffb,
                                                          const float* __restrict__ b1,
                                                          const float* __restrict__ b2,
                                                          float* __restrict__ out){
    __shared__ bf16 xs[16][264];        // ctx -> x -> xhat -> h1 (reused)
    int n = blockIdx.x & 7, b = blockIdx.x >> 3, qt = blockIdx.y;
    int tid = threadIdx.x;
    int h = tid >> 6, lane = tid & 63;
    int lg = lane >> 4, li = lane & 15;

    // Q B-frag resident: q = qt*16 + li
    short8 qB[2];
    #pragma unroll
    for(int ks = 0; ks < 2; ks++)
        qB[ks] = *(const short8*)(qn + (b * V + qt * 16 + li) * F + h * DQ + ks * 32 + lg * 8);

    f32x4 o[4];
    #pragma unroll
    for(int dt = 0; dt < 4; dt++) o[dt] = (f32x4){0.f,0.f,0.f,0.f};
    float l_acc = 0.f;

    const float scale = 0.125f;
    int g1 = lg & 1;
    int lhA = li | ((2 * g1) << 4);
    int lhB = lhA | 16;
    bool hi = lane >= 32;
    int fel = lg * 128 + li * 8;

    for(int kc = 0; kc < 16; kc++){
        int fb = ((n * 16 + kc) * 2) * 8 + h * 2;
        short8 kA00 = *(const short8*)(k4 + (fb + 0) * 512 + fel);
        short8 kA01 = *(const short8*)(k4 + (fb + 1) * 512 + fel);
        short8 kA10 = *(const short8*)(k4 + (fb + 8) * 512 + fel);
        short8 kA11 = *(const short8*)(k4 + (fb + 9) * 512 + fel);

        // S^T = K·Q^T : lane holds S[q = li][key = kc*32 + kt*16 + lg*4 + r]
        f32x4 st0 = (f32x4){0.f,0.f,0.f,0.f};
        f32x4 st1 = (f32x4){0.f,0.f,0.f,0.f};
        st0 = MFMA(kA00, qB[0], st0);
        st1 = MFMA(kA10, qB[0], st1);
        st0 = MFMA(kA01, qB[1], st0);
        st1 = MFMA(kA11, qB[1], st1);

        // exp (no max: bounded scores, ratio-invariant)
        float p[2][4], rsum = 0.f;
        #pragma unroll
        for(int r = 0; r < 4; r++){
            p[0][r] = __expf(st0[r] * scale);
            p[1][r] = __expf(st1[r] * scale);
            rsum += p[0][r] + p[1][r];
        }
        l_acc += rsum;

        unsigned pk00 = pack2bf(p[0][0], p[0][1]);
        unsigned pk01 = pack2bf(p[0][2], p[0][3]);
        unsigned pk10 = pack2bf(p[1][0], p[1][1]);
        unsigned pk11 = pack2bf(p[1][2], p[1][3]);

        // P^T C-layout -> B-frag via register shuffles
        unsigned d0a = __shfl((int)pk00, lhA, 64);
        unsigned d0b = __shfl((int)pk10, lhA, 64);
        unsigned d1a = __shfl((int)pk01, lhA, 64);
        unsigned d1b = __shfl((int)pk11, lhA, 64);
        unsigned d2a = __shfl((int)pk00, lhB, 64);
        unsigned d2b = __shfl((int)pk10, lhB, 64);
        unsigned d3a = __shfl((int)pk01, lhB, 64);
        unsigned d3b = __shfl((int)pk11, lhB, 64);
        uint4v uv;
        uv.x = hi ? d0b : d0a;
        uv.y = hi ? d1b : d1a;
        uv.z = hi ? d2b : d2a;
        uv.w = hi ? d3b : d3a;
        short8 pfrag = __builtin_bit_cast(short8, uv);

        // O^T += V^T · P^T
        const bf16* vb = v4 + ((n * 16 + kc) * F + h * DQ) * 32;
        #pragma unroll
        for(int dt = 0; dt < 4; dt++){
            short8 vA = *(const short8*)(vb + (dt * 16 + li) * 32 + lg * 8);
            o[dt] = MFMA(vA, pfrag, o[dt]);
        }
    }

    l_acc += __shfl_xor(l_acc, 16);
    l_acc += __shfl_xor(l_acc, 32);
    float inv = 1.0f / l_acc;

    // stage normalized O to LDS as ctx[q][col]
    #pragma unroll
    for(int dt = 0; dt < 4; dt++){
        uint2 pkd;
        pkd.x = pack2bf(o[dt][0] * inv, o[dt][1] * inv);
        pkd.y = pack2bf(o[dt][2] * inv, o[dt][3] * inv);
        *(uint2*)&xs[li][h * DQ + dt * 16 + lg * 4] = pkd;
    }
    __syncthreads();

    // ---- Wo GEMM + bo + tex residual -> xres (registers, fp32). wave h -> cols h*64..+64
    const bf16* Wo = wbf + 3 * (F * F);
    int colbase = h * 64;
    f32x4 xac[4];
    #pragma unroll
    for(int ni = 0; ni < 4; ni++) xac[ni] = (f32x4){0.f,0.f,0.f,0.f};
    #pragma unroll
    for(int kc = 0; kc < 8; kc++){
        short8 a0 = *(const short8*)&xs[li][kc * 32 + lg * 8];
        #pragma unroll
        for(int ni = 0; ni < 4; ni++){
            short8 bw = *(const short8*)(Wo + (colbase + ni * 16 + li) * F + kc * 32 + lg * 8);
            xac[ni] = MFMA(a0, bw, xac[ni]);
        }
    }
    float xres[4][4];
    #pragma unroll
    for(int ni = 0; ni < 4; ni++)
        #pragma unroll
        for(int r = 0; r < 4; r++){
            int qrel = lg * 4 + r;
            int col = colbase + ni * 16 + li;
            xres[ni][r] = xac[ni][r] + bo[col] + b2f(tb[(b * V + qt * 16 + qrel) * F + col]);
        }
    __syncthreads();                  // ctx reads done
    #pragma unroll
    for(int ni = 0; ni < 4; ni++)
        #pragma unroll
        for(int r = 0; r < 4; r++)
            xs[lg * 4 + r][colbase + ni * 16 + li] = __float2bfloat16(xres[ni][r]);
    __syncthreads();

    // ---- ffln LN: row = tid>>4 (16 rows), 16 threads/row; stats via 16-lane shuffles
    int row = tid >> 4, sub = tid & 15;
    short8 xa  = *(const short8*)&xs[row][sub * 16];
    short8 xb2 = *(const short8*)&xs[row][sub * 16 + 8];
    float sum = 0.f, sq = 0.f;
    #pragma unroll
    for(int j = 0; j < 8; j++){
        float v0 = shf(xa[j]), v1 = shf(xb2[j]);
        sum += v0 + v1; sq += v0 * v0 + v1 * v1;
    }
    #pragma unroll
    for(int m = 1; m < 16; m <<= 1){ sum += __shfl_xor(sum, m); sq += __shfl_xor(sq, m); }
    float mu = sum * (1.0f / F);
    float var = sq * (1.0f / F) - mu * mu;
    float rsv = rsqrtf(var + EPS);
    {
        float nv[16];
        #pragma unroll
        for(int j = 0; j < 8; j++){
            int c0 = sub * 16 + j, c1 = sub * 16 + 8 + j;
            nv[j]     = (shf(xa[j])  - mu) * rsv * ffg[c0] + ffb[c0];
            nv[8 + j] = (shf(xb2[j]) - mu) * rsv * ffg[c1] + ffb[c1];
        }
        uint4v pa, pb;
        pa.x = pack2bf(nv[0], nv[1]);  pa.y = pack2bf(nv[2], nv[3]);
        pa.z = pack2bf(nv[4], nv[5]);  pa.w = pack2bf(nv[6], nv[7]);
        pb.x = pack2bf(nv[8], nv[9]);  pb.y = pack2bf(nv[10], nv[11]);
        pb.z = pack2bf(nv[12], nv[13]); pb.w = pack2bf(nv[14], nv[15]);
        *(short8*)&xs[row][sub * 16]     = __builtin_bit_cast(short8, pa);
        *(short8*)&xs[row][sub * 16 + 8] = __builtin_bit_cast(short8, pb);
    }
    __syncthreads();

    // ---- GEMM1: h = relu(xhat @ W1^T + b1)
    const bf16* W1b = wbf + 4 * (F * F);
    f32x4 hac[4];
    #pragma unroll
    for(int ni = 0; ni < 4; ni++) hac[ni] = (f32x4){0.f,0.f,0.f,0.f};
    #pragma unroll
    for(int kc = 0; kc < 8; kc++){
        short8 a0 = *(const short8*)&xs[li][kc * 32 + lg * 8];
        #pragma unroll
        for(int ni = 0; ni < 4; ni++){
            short8 bw = *(const short8*)(W1b + (colbase + ni * 16 + li) * F + kc * 32 + lg * 8);
            hac[ni] = MFMA(a0, bw, hac[ni]);
        }
    }
    __syncthreads();                  // xhat reads done
    #pragma unroll
    for(int ni = 0; ni < 4; ni++)
        #pragma unroll
        for(int r = 0; r < 4; r++){
            int col = colbase + ni * 16 + li;
            xs[lg * 4 + r][col] = __float2bfloat16(fmaxf(hac[ni][r] + b1[col], 0.f));
        }
    __syncthreads();

    // ---- GEMM2: out = x + h @ W2^T + b2
    const bf16* W2b = wbf + 5 * (F * F);
    f32x4 oac[4];
    #pragma unroll
    for(int ni = 0; ni < 4; ni++) oac[ni] = (f32x4){0.f,0.f,0.f,0.f};
    #pragma unroll
    for(int kc = 0; kc < 8; kc++){
        short8 a0 = *(const short8*)&xs[li][kc * 32 + lg * 8];
        #pragma unroll
        for(int ni = 0; ni < 4; ni++){
            short8 bw = *(const short8*)(W2b + (colbase + ni * 16 + li) * F + kc * 32 + lg * 8);
            oac[ni] = MFMA(a0, bw, oac[ni]);
        }
    }
    #pragma unroll
    for(int ni = 0; ni < 4; ni++)
        #pragma unroll
        for(int r = 0; r < 4; r++){
            int qrel = lg * 4 + r;
            int ro = (b * NC + n) * V + qt * 16 + qrel;
            int col = colbase + ni * 16 + li;
            out[ro * F + col] = oac[ni][r] + b2[col] + xres[ni][r];
        }
}

extern "C" void kernel_launch(void* const* d_in, const int* in_sizes, int n_in,
                              void* d_out, int out_size, void* d_ws, size_t ws_size,
                              hipStream_t stream) {
    const float* code_map = (const float*)d_in[0];
    const float* tex_map  = (const float*)d_in[1];
    const float* Wq = (const float*)d_in[2];  const float* bq = (const float*)d_in[3];
    const float* Wk = (const float*)d_in[4];  const float* bk = (const float*)d_in[5];
    const float* Wv = (const float*)d_in[6];  const float* bv = (const float*)d_in[7];
    const float* Wo = (const float*)d_in[8];  const float* bo = (const float*)d_in[9];
    const float* ln1_g = (const float*)d_in[10]; const float* ln1_b = (const float*)d_in[11];
    const float* ln2_g = (const float*)d_in[12]; const float* ln2_b = (const float*)d_in[13];
    const float* ffln_g = (const float*)d_in[14]; const float* ffln_b = (const float*)d_in[15];
    const float* W1 = (const float*)d_in[16]; const float* b1 = (const float*)d_in[17];
    const float* W2 = (const float*)d_in[18]; const float* b2 = (const float*)d_in[19];
    float* out = (float*)d_out;

    // ws layout (bf16 elements)
    bf16* ws  = (bf16*)d_ws;
    bf16* qn  = ws;                       // 4096*256     = 1048576
    bf16* k4  = qn + 1048576;             // 1048576 (A-frag layout)
    bf16* v4  = k4 + 1048576;             // 1048576
    bf16* cn  = v4 + 1048576;             // 1048576
    bf16* tn  = cn + 1048576;             // 1048576
    bf16* tb  = tn + 1048576;             // 1048576 (bf16 texture copy)
    bf16* wbf = tb + 1048576;             // 6*256*256    = 393216 (Wq,Wk,Wv,Wo,W1,W2)

    castw_kernel<<<6 * 256, 256, 0, stream>>>(Wq, Wk, Wv, Wo, W1, W2, wbf);
    ln_kernel<<<8192, 256, 0, stream>>>(code_map, tex_map, ln1_g, ln1_b, ln2_g, ln2_b, cn, tn, tb);
    qkvgemm_kernel<<<dim3(64, 4, 3), 256, 0, stream>>>(cn, tn, wbf, bq, bk, bv, qn, k4, v4);
    attn_mlp_kernel<<<dim3(64, 32), 256, 0, stream>>>(qn, k4, v4, wbf, bo, tb,
                                                      ffln_g, ffln_b, b1, b2, out);
}